// Round 1
// baseline (1278.456 us; speedup 1.0000x reference)
//
#include <hip/hip_runtime.h>
#include <cstddef>
#include <cstdint>

// ---------------------------------------------------------------------------
// Problem geometry (fixed): x [N=32, C=256, H=64, W=64] fp32.
// Split into 4 groups of Cb=64 channels. Branch b=0 (sq): 3x3 pad(1,1) on
// channels 64..127; b=1 (ver): 3x1 pad(1,0) on 128..191; b=2 (hor): 1x3
// pad(0,1) on 192..255. CondConv K=4 experts. Then training-mode BN per
// branch, concat(s0,sq,ve,ho), channel_shuffle(g=8):
//   out_channel(c_pre) = (c_pre % 32)*8 + c_pre/32
// ---------------------------------------------------------------------------

#define HW 4096               // 64*64
#define NB 32                 // batch
#define CB 64                 // channels per branch
#define CNT_INV (1.0f / 131072.0f)   // 1/(N*H*W)

// workspace layout (floats)
#define WS_POOLED 0                          // [3][32][64]
#define WS_ATT    6144                       // [3][32][4]
#define WS_PSTATS 6528                       // [3][64][32][2]  per-(o,n) partial sums
#define WS_SS     18816                      // [3][64][2]      scale/shift
#define WS_AGG_SQ 19200                      // [32][64][64][9]
#define WS_AGG_VER (WS_AGG_SQ + 32*64*64*9)  // [32][64][64][3]
#define WS_AGG_HOR (WS_AGG_VER + 32*64*64*3) // [32][64][64][3]

__device__ __forceinline__ int shuf_ch(int c_pre) {
    return ((c_pre & 31) << 3) | (c_pre >> 5);
}

// ---- 1. pooled mean over HxW for the 3 conv branches -----------------------
__global__ void __launch_bounds__(256) pool_kernel(const float* __restrict__ x,
                                                   float* __restrict__ pooled) {
    int bid = blockIdx.x;                 // (b*32+n)*64 + c, 6144 total
    int c = bid & 63;
    int n = (bid >> 6) & 31;
    int b = bid >> 11;
    const float4* xp = (const float4*)(x + (size_t)(n * 256 + 64 * (b + 1) + c) * HW);
    int tid = threadIdx.x;
    float s = 0.f;
#pragma unroll
    for (int it = 0; it < 4; ++it) {
        float4 v = xp[tid + it * 256];
        s += (v.x + v.y) + (v.z + v.w);
    }
#pragma unroll
    for (int off = 32; off; off >>= 1) s += __shfl_down(s, off, 64);
    __shared__ float r[4];
    if ((tid & 63) == 0) r[tid >> 6] = s;
    __syncthreads();
    if (tid == 0) pooled[bid] = (r[0] + r[1] + r[2] + r[3]) * (1.f / 4096.f);
}

// ---- 2. attention: sigmoid(pooled @ att_w.T + att_b) -----------------------
__global__ void att_kernel(const float* __restrict__ pooled,
                           const float* __restrict__ aw,
                           const float* __restrict__ ab,
                           float* __restrict__ att, int b) {
    int n = blockIdx.x;                   // 32 blocks, 64 threads
    int t = threadIdx.x;
    float p = pooled[(b * 32 + n) * 64 + t];
#pragma unroll
    for (int k = 0; k < 4; ++k) {
        float v = p * aw[k * 64 + t];
#pragma unroll
        for (int off = 32; off; off >>= 1) v += __shfl_down(v, off, 64);
        if (t == 0) att[(b * 32 + n) * 4 + k] = 1.f / (1.f + expf(-(v + ab[k])));
    }
}

// ---- 3. aggregate per-sample weights: agg[n] = sum_k att[n,k]*w[k] ---------
template <int TAPS>
__global__ void __launch_bounds__(256) agg_kernel(const float* __restrict__ w,
                                                  const float* __restrict__ att,
                                                  float* __restrict__ aggw, int b) {
    constexpr int PS = 64 * 64 * TAPS;
    int idx = blockIdx.x * 256 + threadIdx.x;
    if (idx >= 32 * PS) return;
    int n = idx / PS;
    int r = idx - n * PS;
    const float* a = att + (b * 32 + n) * 4;
    aggw[idx] = a[0] * w[r] + a[1] * w[PS + r] + a[2] * w[2 * PS + r] + a[3] * w[3 * PS + r];
}

// ---- 4. per-sample conv, direct write to shuffled out channel + BN partials
template <int KH, int KW, int PH, int PW>
__global__ void __launch_bounds__(256) condconv_kernel(
    const float* __restrict__ x, const float* __restrict__ aggw,
    float* __restrict__ out, float* __restrict__ pstats, int cbase) {
    constexpr int TAPS = KH * KW;
    constexpr int OG = 4;                  // output channels per block
    const int o0 = blockIdx.x * OG;        // blockIdx.x in [0,16)
    const int n = blockIdx.y;              // [0,32)
    const int tid = threadIdx.x;
    const int w = tid & 63;                // fixed column per thread
    const int h0 = tid >> 6;               // row phase 0..3

    __shared__ float wl[OG][64][TAPS];
    const float* wsrc = aggw + ((size_t)n * 64 + o0) * 64 * TAPS;
    for (int idx = tid; idx < OG * 64 * TAPS; idx += 256)
        ((float*)wl)[idx] = wsrc[idx];
    __syncthreads();

    const float* xin = x + (size_t)(n * 256 + cbase) * HW;

    float s1a[OG], s2a[OG];
#pragma unroll
    for (int o = 0; o < OG; ++o) { s1a[o] = 0.f; s2a[o] = 0.f; }

    for (int j = 0; j < 16; ++j) {
        const int h = h0 + j * 4;
        float acc[OG];
#pragma unroll
        for (int o = 0; o < OG; ++o) acc[o] = 0.f;
        for (int i = 0; i < 64; ++i) {
            const float* xp = xin + i * HW;
            float xv[TAPS];
#pragma unroll
            for (int kh = 0; kh < KH; ++kh) {
                const int ih = h + kh - PH;
                const bool hok = (unsigned)ih < 64u;
#pragma unroll
                for (int kw = 0; kw < KW; ++kw) {
                    const int iw = w + kw - PW;
                    const bool ok = hok && ((unsigned)iw < 64u);
                    xv[kh * KW + kw] = ok ? xp[ih * 64 + iw] : 0.f;
                }
            }
#pragma unroll
            for (int o = 0; o < OG; ++o)
#pragma unroll
                for (int t = 0; t < TAPS; ++t)
                    acc[o] = fmaf(xv[t], wl[o][i][t], acc[o]);
        }
#pragma unroll
        for (int o = 0; o < OG; ++o) {
            const int c_pre = cbase + o0 + o;
            const int c_out = shuf_ch(c_pre);
            out[(size_t)(n * 256 + c_out) * HW + h * 64 + w] = acc[o];
            s1a[o] += acc[o];
            s2a[o] += acc[o] * acc[o];
        }
    }

    // block-reduce BN partial sums per output channel (deterministic: unique slot)
    __shared__ float red[2][4][OG];
#pragma unroll
    for (int o = 0; o < OG; ++o) {
        float a = s1a[o], bb = s2a[o];
#pragma unroll
        for (int off = 32; off; off >>= 1) {
            a += __shfl_down(a, off, 64);
            bb += __shfl_down(bb, off, 64);
        }
        if ((tid & 63) == 0) { red[0][tid >> 6][o] = a; red[1][tid >> 6][o] = bb; }
    }
    __syncthreads();
    if (tid < OG) {
        int o = tid;
        float ta = red[0][0][o] + red[0][1][o] + red[0][2][o] + red[0][3][o];
        float tb = red[1][0][o] + red[1][1][o] + red[1][2][o] + red[1][3][o];
        pstats[((o0 + o) * 32 + n) * 2 + 0] = ta;
        pstats[((o0 + o) * 32 + n) * 2 + 1] = tb;
    }
}

// ---- 5. copy s0 (identity branch) into shuffled positions ------------------
__global__ void __launch_bounds__(256) s0_kernel(const float* __restrict__ x,
                                                 float* __restrict__ out) {
    int idx = blockIdx.x * 256 + threadIdx.x;   // 2,097,152 float4 total
    int p4 = idx & 1023;
    int c = (idx >> 10) & 63;
    int n = idx >> 16;
    int c_out = shuf_ch(c);
    const float4* src = (const float4*)(x + (size_t)(n * 256 + c) * HW);
    float4* dst = (float4*)(out + (size_t)(n * 256 + c_out) * HW);
    dst[p4] = src[p4];
}

// ---- 6. finalize BN: scale/shift per channel -------------------------------
__global__ void finalize_kernel(const float* __restrict__ pstats,
                                const float* __restrict__ gamma,
                                const float* __restrict__ beta,
                                float* __restrict__ ss) {
    int o = threadIdx.x;                  // 64 threads
    float s = 0.f, q = 0.f;
    for (int n = 0; n < 32; ++n) {
        s += pstats[(o * 32 + n) * 2 + 0];
        q += pstats[(o * 32 + n) * 2 + 1];
    }
    float mean = s * CNT_INV;
    float var = q * CNT_INV - mean * mean;
    float scale = rsqrtf(var + 1e-5f) * gamma[o];
    ss[o * 2 + 0] = scale;
    ss[o * 2 + 1] = beta[o] - mean * scale;
}

// ---- 7. apply BN in-place on d_out -----------------------------------------
__global__ void __launch_bounds__(256) bn_kernel(float* __restrict__ out,
                                                 const float* __restrict__ ss,
                                                 int cbase) {
    int bid = blockIdx.x;                 // 64*32*4 = 8192
    int chunk = bid & 3;
    int n = (bid >> 2) & 31;
    int o = bid >> 7;
    float scale = ss[o * 2], shift = ss[o * 2 + 1];
    int c_out = shuf_ch(cbase + o);
    float4* p = (float4*)(out + (size_t)(n * 256 + c_out) * HW) + chunk * 256 + threadIdx.x;
    float4 v = *p;
    v.x = fmaf(v.x, scale, shift);
    v.y = fmaf(v.y, scale, shift);
    v.z = fmaf(v.z, scale, shift);
    v.w = fmaf(v.w, scale, shift);
    *p = v;
}

extern "C" void kernel_launch(void* const* d_in, const int* in_sizes, int n_in,
                              void* d_out, int out_size, void* d_ws, size_t ws_size,
                              hipStream_t stream) {
    const float* x        = (const float*)d_in[0];
    const float* sq_att_w = (const float*)d_in[1];
    const float* sq_att_b = (const float*)d_in[2];
    const float* sq_w     = (const float*)d_in[3];
    const float* sq_g     = (const float*)d_in[4];
    const float* sq_b     = (const float*)d_in[5];
    const float* ver_att_w= (const float*)d_in[6];
    const float* ver_att_b= (const float*)d_in[7];
    const float* ver_w    = (const float*)d_in[8];
    const float* ver_g    = (const float*)d_in[9];
    const float* ver_b    = (const float*)d_in[10];
    const float* hor_att_w= (const float*)d_in[11];
    const float* hor_att_b= (const float*)d_in[12];
    const float* hor_w    = (const float*)d_in[13];
    const float* hor_g    = (const float*)d_in[14];
    const float* hor_b    = (const float*)d_in[15];
    float* out = (float*)d_out;
    float* ws = (float*)d_ws;

    float* pooled  = ws + WS_POOLED;
    float* att     = ws + WS_ATT;
    float* pstats  = ws + WS_PSTATS;
    float* ss      = ws + WS_SS;
    float* agg_sq  = ws + WS_AGG_SQ;
    float* agg_ver = ws + WS_AGG_VER;
    float* agg_hor = ws + WS_AGG_HOR;

    pool_kernel<<<6144, 256, 0, stream>>>(x, pooled);
    att_kernel<<<32, 64, 0, stream>>>(pooled, sq_att_w, sq_att_b, att, 0);
    att_kernel<<<32, 64, 0, stream>>>(pooled, ver_att_w, ver_att_b, att, 1);
    att_kernel<<<32, 64, 0, stream>>>(pooled, hor_att_w, hor_att_b, att, 2);
    agg_kernel<9><<<4608, 256, 0, stream>>>(sq_w, att, agg_sq, 0);
    agg_kernel<3><<<1536, 256, 0, stream>>>(ver_w, att, agg_ver, 1);
    agg_kernel<3><<<1536, 256, 0, stream>>>(hor_w, att, agg_hor, 2);

    condconv_kernel<3, 3, 1, 1><<<dim3(16, 32), 256, 0, stream>>>(x, agg_sq, out, pstats, 64);
    condconv_kernel<3, 1, 1, 0><<<dim3(16, 32), 256, 0, stream>>>(x, agg_ver, out, pstats + 64 * 32 * 2, 128);
    condconv_kernel<1, 3, 0, 1><<<dim3(16, 32), 256, 0, stream>>>(x, agg_hor, out, pstats + 2 * 64 * 32 * 2, 192);

    s0_kernel<<<8192, 256, 0, stream>>>(x, out);

    finalize_kernel<<<1, 64, 0, stream>>>(pstats, sq_g, sq_b, ss);
    finalize_kernel<<<1, 64, 0, stream>>>(pstats + 64 * 32 * 2, ver_g, ver_b, ss + 128);
    finalize_kernel<<<1, 64, 0, stream>>>(pstats + 2 * 64 * 32 * 2, hor_g, hor_b, ss + 256);

    bn_kernel<<<8192, 256, 0, stream>>>(out, ss, 64);
    bn_kernel<<<8192, 256, 0, stream>>>(out, ss + 128, 128);
    bn_kernel<<<8192, 256, 0, stream>>>(out, ss + 256, 192);
}

// Round 2
// 265.995 us; speedup vs baseline: 4.8063x; 4.8063x over previous
//
#include <hip/hip_runtime.h>
#include <cstddef>
#include <cstdint>

// ---------------------------------------------------------------------------
// x [N=32, C=256, H=64, W=64] fp32. Branches: sq 3x3 pad(1,1) ch 64..127,
// ver 3x1 pad(1,0) ch 128..191, hor 1x3 pad(0,1) ch 192..255. CondConv K=4.
// Training-mode BN per branch, concat(s0,sq,ve,ho), channel_shuffle(g=8):
//   c_out = (c_pre % 32)*8 + c_pre/32
// Conv strategy: per-sample GEMM on matrix cores. O[64,4096] = W[64,K]*X
// with K = taps*64, bf16 inputs, fp32 accum (threshold 0.108 >> bf16 err).
// ---------------------------------------------------------------------------

typedef __attribute__((ext_vector_type(8))) short frag8;    // 8 bf16 = 4 VGPR
typedef __attribute__((ext_vector_type(16))) float accf16;  // 32x32 accum

#define HW 4096
#define CNT_INV (1.0f / 131072.0f)

// workspace offsets (4-byte units)
#define WS_POOLED 0            // 6144
#define WS_ATT    6144         // 384
#define WS_SS     6528         // 384 (3 * 128)
#define WS_PST    6912         // 3 * 262144
#define WS_WBF_SQ  793344      // 589824 u32 (bf16 pairs)
#define WS_WBF_VER 1383168     // 196608
#define WS_WBF_HOR 1579776     // 196608

__device__ __forceinline__ int shuf_ch(int c) { return ((c & 31) << 3) | (c >> 5); }

__device__ __forceinline__ unsigned bf16pair(float a, float b) {
    unsigned ua = __builtin_bit_cast(unsigned, a);
    unsigned ub = __builtin_bit_cast(unsigned, b);
    ua = (ua + 0x7fffu + ((ua >> 16) & 1u)) >> 16;   // round-to-nearest-even
    ub = (ub + 0x7fffu + ((ub >> 16) & 1u)) >> 16;
    return ua | (ub << 16);
}

// ---- 1. pooled mean over HxW for the 3 conv branches -----------------------
__global__ void __launch_bounds__(256) pool_kernel(const float* __restrict__ x,
                                                   float* __restrict__ pooled) {
    int bid = blockIdx.x;                 // (b*32+n)*64 + c, 6144 total
    int c = bid & 63;
    int n = (bid >> 6) & 31;
    int b = bid >> 11;
    const float4* xp = (const float4*)(x + (size_t)(n * 256 + 64 * (b + 1) + c) * HW);
    int tid = threadIdx.x;
    float s = 0.f;
#pragma unroll
    for (int it = 0; it < 4; ++it) {
        float4 v = xp[tid + it * 256];
        s += (v.x + v.y) + (v.z + v.w);
    }
#pragma unroll
    for (int off = 32; off; off >>= 1) s += __shfl_down(s, off, 64);
    __shared__ float r[4];
    if ((tid & 63) == 0) r[tid >> 6] = s;
    __syncthreads();
    if (tid == 0) pooled[bid] = (r[0] + r[1] + r[2] + r[3]) * (1.f / 4096.f);
}

// ---- 2. attention: sigmoid(pooled @ att_w.T + att_b) -----------------------
__global__ void att_kernel(const float* __restrict__ pooled,
                           const float* __restrict__ aw,
                           const float* __restrict__ ab,
                           float* __restrict__ att, int b) {
    int n = blockIdx.x;                   // 32 blocks, 64 threads
    int t = threadIdx.x;
    float p = pooled[(b * 32 + n) * 64 + t];
#pragma unroll
    for (int k = 0; k < 4; ++k) {
        float v = p * aw[k * 64 + t];
#pragma unroll
        for (int off = 32; off; off >>= 1) v += __shfl_down(v, off, 64);
        if (t == 0) att[(b * 32 + n) * 4 + k] = 1.f / (1.f + expf(-(v + ab[k])));
    }
}

// ---- 3. expert-mix weights -> bf16, layout [n][tap][o][i] ------------------
template <int TAPS>
__global__ void __launch_bounds__(256) aggbf_kernel(const float* __restrict__ w,
                                                    const float* __restrict__ att,
                                                    unsigned* __restrict__ wbf, int b) {
    int idx = blockIdx.x * 256 + threadIdx.x;     // ((n*TAPS+t)*64+o)*32+ip
    if (idx >= 32 * TAPS * 2048) return;
    int ip = idx & 31;
    int o  = (idx >> 5) & 63;
    int t  = (idx >> 11) % TAPS;
    int n  = (idx >> 11) / TAPS;
    const float* a = att + (b * 32 + n) * 4;
    constexpr int PS = 64 * 64 * TAPS;
    int base = (o * 64 + ip * 2) * TAPS + t;      // w[k][o][i][t]
    float v0 = a[0]*w[base] + a[1]*w[PS+base] + a[2]*w[2*PS+base] + a[3]*w[3*PS+base];
    int base1 = base + TAPS;
    float v1 = a[0]*w[base1] + a[1]*w[PS+base1] + a[2]*w[2*PS+base1] + a[3]*w[3*PS+base1];
    wbf[idx] = bf16pair(v0, v1);
}

// ---- 4. MFMA conv: block = (row h, sample n), 4 waves 2x2 of 32x32 ---------
template <int KH, int KW, int PH, int PW>
__global__ void __launch_bounds__(256) condconv_mfma(
    const float* __restrict__ x, const unsigned* __restrict__ wbf,
    float* __restrict__ out, float* __restrict__ pst, int cbase) {
    constexpr int TAPS = KH * KW;
    const int h = blockIdx.x;
    const int n = blockIdx.y;
    const int tid = threadIdx.x;
    const int lane = tid & 63;
    const int wv = tid >> 6;              // wave 0..3
    const int wm = wv >> 1, wn = wv & 1;  // 2x2 wave grid (o-half, w-half)
    const int l31 = lane & 31, hi = lane >> 5;
    const int wcol = wn * 32 + l31;       // spatial col this lane owns

    __shared__ __align__(16) unsigned char xs[KH * 8192];   // [r][w][ch] bf16 swz

    // ---- stage KH input rows, transpose to [w][ch], 16B-chunk XOR swizzle
    {
        const int w = tid & 63, pp = tid >> 6;
        const float* xb = x + (size_t)(n * 256 + cbase) * HW;
        for (int r = 0; r < KH; ++r) {
            int hin = h - PH + r;
            bool rok = (unsigned)hin < 64u;
#pragma unroll
            for (int i = 0; i < 8; ++i) {
                int p = pp + i * 4;                         // channel pair 0..31
                float a = 0.f, bb = 0.f;
                if (rok) {
                    a  = xb[(size_t)(2 * p)     * HW + hin * 64 + w];
                    bb = xb[(size_t)(2 * p + 1) * HW + hin * 64 + w];
                }
                int chunk = (p >> 2) ^ (w & 7);
                *(unsigned*)(xs + r * 8192 + w * 128 + chunk * 16 + (p & 3) * 4) =
                    bf16pair(a, bb);
            }
        }
    }

    // ---- preload all A fragments (overlaps with LDS staging before sync)
    frag8 afrag[TAPS][4];
    {
        const frag8* wp = (const frag8*)wbf;
        const int orow = wm * 32 + l31;
#pragma unroll
        for (int t = 0; t < TAPS; ++t)
#pragma unroll
            for (int kk = 0; kk < 4; ++kk)
                afrag[t][kk] = wp[(size_t)((n * TAPS + t) * 64 + orow) * 8 + kk * 2 + hi];
    }
    __syncthreads();

    // ---- main loop: taps x 4 k-steps of K=16
    accf16 acc = {};
    const frag8 zz = {};
#pragma unroll
    for (int t = 0; t < TAPS; ++t) {
        const int r = t / KW;
        const int dw = t % KW - PW;
        int s = wcol + dw;
        bool valid = (unsigned)s < 64u;
        int sc = valid ? s : 0;
        const unsigned char* bp = xs + r * 8192 + sc * 128;
#pragma unroll
        for (int kk = 0; kk < 4; ++kk) {
            frag8 bfr = *(const frag8*)(bp + (((kk * 2 + hi) ^ (sc & 7)) * 16));
            bfr = valid ? bfr : zz;
            acc = __builtin_amdgcn_mfma_f32_32x32x16_bf16(afrag[t][kk], bfr, acc, 0, 0, 0);
        }
    }

    // ---- C write to shuffled channels (col=lane&31, row=(rg&3)+8*(rg>>2)+4*hi)
    {
        float* ob = out + (size_t)n * 256 * HW + h * 64 + wcol;
#pragma unroll
        for (int rg = 0; rg < 16; ++rg) {
            int o = wm * 32 + (rg & 3) + 8 * (rg >> 2) + 4 * hi;
            ob[(size_t)shuf_ch(cbase + o) * HW] = acc[rg];
        }
    }

    // ---- BN partial sums -> unique slot per (o, n, h)
    __shared__ float red1[4][2][16];
    __shared__ float red2[4][2][16];
#pragma unroll
    for (int rg = 0; rg < 16; ++rg) {
        float v1 = acc[rg];
        float v2 = v1 * v1;
#pragma unroll
        for (int off = 16; off; off >>= 1) {
            v1 += __shfl_down(v1, off, 32);
            v2 += __shfl_down(v2, off, 32);
        }
        if (l31 == 0) { red1[wv][hi][rg] = v1; red2[wv][hi][rg] = v2; }
    }
    __syncthreads();
    if (tid < 64) {
        int rg = tid & 15, hi2 = (tid >> 4) & 1, wm2 = tid >> 5;
        float s1 = red1[wm2 * 2][hi2][rg] + red1[wm2 * 2 + 1][hi2][rg];
        float s2 = red2[wm2 * 2][hi2][rg] + red2[wm2 * 2 + 1][hi2][rg];
        int o = wm2 * 32 + (rg & 3) + 8 * (rg >> 2) + 4 * hi2;
        int slot = n * 64 + h;
        pst[o * 4096 + slot] = s1;
        pst[o * 4096 + 2048 + slot] = s2;
    }
}

// ---- 5. copy s0 (identity branch) into shuffled positions ------------------
__global__ void __launch_bounds__(256) s0_kernel(const float* __restrict__ x,
                                                 float* __restrict__ out) {
    int idx = blockIdx.x * 256 + threadIdx.x;
    int p4 = idx & 1023;
    int c = (idx >> 10) & 63;
    int n = idx >> 16;
    int c_out = shuf_ch(c);
    const float4* src = (const float4*)(x + (size_t)(n * 256 + c) * HW);
    float4* dst = (float4*)(out + (size_t)(n * 256 + c_out) * HW);
    dst[p4] = src[p4];
}

// ---- 6. reduce BN partials -> scale/shift ----------------------------------
__global__ void __launch_bounds__(256) bnstats_kernel(const float* __restrict__ pst,
                                                      const float* __restrict__ gamma,
                                                      const float* __restrict__ beta,
                                                      float* __restrict__ ss) {
    int o = blockIdx.x, t = threadIdx.x;
    float s1 = 0.f, s2 = 0.f;
    for (int i = t; i < 2048; i += 256) {
        s1 += pst[o * 4096 + i];
        s2 += pst[o * 4096 + 2048 + i];
    }
#pragma unroll
    for (int off = 32; off; off >>= 1) {
        s1 += __shfl_down(s1, off, 64);
        s2 += __shfl_down(s2, off, 64);
    }
    __shared__ float r1[4], r2[4];
    if ((t & 63) == 0) { r1[t >> 6] = s1; r2[t >> 6] = s2; }
    __syncthreads();
    if (t == 0) {
        float S1 = r1[0] + r1[1] + r1[2] + r1[3];
        float S2 = r2[0] + r2[1] + r2[2] + r2[3];
        float mean = S1 * CNT_INV;
        float var = S2 * CNT_INV - mean * mean;
        float scale = rsqrtf(var + 1e-5f) * gamma[o];
        ss[o * 2 + 0] = scale;
        ss[o * 2 + 1] = beta[o] - mean * scale;
    }
}

// ---- 7. apply BN in-place on d_out -----------------------------------------
__global__ void __launch_bounds__(256) bn_kernel(float* __restrict__ out,
                                                 const float* __restrict__ ss,
                                                 int cbase) {
    int bid = blockIdx.x;                 // 64*32*4 = 8192
    int chunk = bid & 3;
    int n = (bid >> 2) & 31;
    int o = bid >> 7;
    float scale = ss[o * 2], shift = ss[o * 2 + 1];
    int c_out = shuf_ch(cbase + o);
    float4* p = (float4*)(out + (size_t)(n * 256 + c_out) * HW) + chunk * 256 + threadIdx.x;
    float4 v = *p;
    v.x = fmaf(v.x, scale, shift);
    v.y = fmaf(v.y, scale, shift);
    v.z = fmaf(v.z, scale, shift);
    v.w = fmaf(v.w, scale, shift);
    *p = v;
}

extern "C" void kernel_launch(void* const* d_in, const int* in_sizes, int n_in,
                              void* d_out, int out_size, void* d_ws, size_t ws_size,
                              hipStream_t stream) {
    const float* x        = (const float*)d_in[0];
    const float* sq_att_w = (const float*)d_in[1];
    const float* sq_att_b = (const float*)d_in[2];
    const float* sq_w     = (const float*)d_in[3];
    const float* sq_g     = (const float*)d_in[4];
    const float* sq_b     = (const float*)d_in[5];
    const float* ver_att_w= (const float*)d_in[6];
    const float* ver_att_b= (const float*)d_in[7];
    const float* ver_w    = (const float*)d_in[8];
    const float* ver_g    = (const float*)d_in[9];
    const float* ver_b    = (const float*)d_in[10];
    const float* hor_att_w= (const float*)d_in[11];
    const float* hor_att_b= (const float*)d_in[12];
    const float* hor_w    = (const float*)d_in[13];
    const float* hor_g    = (const float*)d_in[14];
    const float* hor_b    = (const float*)d_in[15];
    float* out = (float*)d_out;
    float* ws = (float*)d_ws;

    float* pooled = ws + WS_POOLED;
    float* att    = ws + WS_ATT;
    float* ss     = ws + WS_SS;
    float* pst    = ws + WS_PST;
    unsigned* wbf_sq  = (unsigned*)(ws + WS_WBF_SQ);
    unsigned* wbf_ver = (unsigned*)(ws + WS_WBF_VER);
    unsigned* wbf_hor = (unsigned*)(ws + WS_WBF_HOR);

    pool_kernel<<<6144, 256, 0, stream>>>(x, pooled);
    att_kernel<<<32, 64, 0, stream>>>(pooled, sq_att_w, sq_att_b, att, 0);
    att_kernel<<<32, 64, 0, stream>>>(pooled, ver_att_w, ver_att_b, att, 1);
    att_kernel<<<32, 64, 0, stream>>>(pooled, hor_att_w, hor_att_b, att, 2);

    aggbf_kernel<9><<<2304, 256, 0, stream>>>(sq_w, att, wbf_sq, 0);
    aggbf_kernel<3><<<768, 256, 0, stream>>>(ver_w, att, wbf_ver, 1);
    aggbf_kernel<3><<<768, 256, 0, stream>>>(hor_w, att, wbf_hor, 2);

    condconv_mfma<3, 3, 1, 1><<<dim3(64, 32), 256, 0, stream>>>(x, wbf_sq, out, pst, 64);
    condconv_mfma<3, 1, 1, 0><<<dim3(64, 32), 256, 0, stream>>>(x, wbf_ver, out, pst + 262144, 128);
    condconv_mfma<1, 3, 0, 1><<<dim3(64, 32), 256, 0, stream>>>(x, wbf_hor, out, pst + 2 * 262144, 192);

    s0_kernel<<<8192, 256, 0, stream>>>(x, out);

    bnstats_kernel<<<64, 256, 0, stream>>>(pst, sq_g, sq_b, ss);
    bnstats_kernel<<<64, 256, 0, stream>>>(pst + 262144, ver_g, ver_b, ss + 128);
    bnstats_kernel<<<64, 256, 0, stream>>>(pst + 2 * 262144, hor_g, hor_b, ss + 256);

    bn_kernel<<<8192, 256, 0, stream>>>(out, ss, 64);
    bn_kernel<<<8192, 256, 0, stream>>>(out, ss + 128, 128);
    bn_kernel<<<8192, 256, 0, stream>>>(out, ss + 256, 192);
}

// Round 3
// 184.656 us; speedup vs baseline: 6.9234x; 1.4405x over previous
//
#include <hip/hip_runtime.h>
#include <cstddef>
#include <cstdint>

// ---------------------------------------------------------------------------
// x [N=32, C=256, H=64, W=64] fp32. Branches: sq 3x3 pad(1,1) ch 64..127,
// ver 3x1 pad(1,0) ch 128..191, hor 1x3 pad(0,1) ch 192..255. CondConv K=4.
// Training-mode BN per branch, concat(s0,sq,ve,ho), channel_shuffle(g=8):
//   c_out = (c_pre % 32)*8 + c_pre/32
// Conv: per-sample GEMM on matrix cores, bf16 in / fp32 accum.
// Block = (4 output rows, sample). LDS x-tile chunk-major [row][ch/8][w+1]
// so ds_write_b128 and ds_read_b128 are both lane-consecutive (0 conflicts).
// A-fragments double-buffered 2 taps deep (prefetch 1 ahead), never all-resident.
// ---------------------------------------------------------------------------

typedef __attribute__((ext_vector_type(8))) short frag8;    // 8 bf16 = 4 VGPR
typedef __attribute__((ext_vector_type(16))) float accf16;  // 32x32 accum

#define HW 4096
#define CNT_INV (1.0f / 131072.0f)

// workspace offsets (4-byte units)
#define WS_POOLED 0            // 6144
#define WS_ATT    6144         // 384
#define WS_SS     6528         // 384 (3 * 128)
#define WS_PST    6912         // 3 * 65536
#define WS_WBF_SQ  203520      // 589824 u32 (bf16 pairs)
#define WS_WBF_VER 793344      // 196608
#define WS_WBF_HOR 989952      // 196608

__device__ __forceinline__ int shuf_ch(int c) { return ((c & 31) << 3) | (c >> 5); }

__device__ __forceinline__ unsigned bf16pair(float a, float b) {
    unsigned ua = __builtin_bit_cast(unsigned, a);
    unsigned ub = __builtin_bit_cast(unsigned, b);
    ua = (ua + 0x7fffu + ((ua >> 16) & 1u)) >> 16;   // round-to-nearest-even
    ub = (ub + 0x7fffu + ((ub >> 16) & 1u)) >> 16;
    return ua | (ub << 16);
}

// ---- 1. pooled mean over HxW for the 3 conv branches -----------------------
__global__ void __launch_bounds__(256) pool_kernel(const float* __restrict__ x,
                                                   float* __restrict__ pooled) {
    int bid = blockIdx.x;                 // (b*32+n)*64 + c, 6144 total
    int c = bid & 63;
    int n = (bid >> 6) & 31;
    int b = bid >> 11;
    const float4* xp = (const float4*)(x + (size_t)(n * 256 + 64 * (b + 1) + c) * HW);
    int tid = threadIdx.x;
    float s = 0.f;
#pragma unroll
    for (int it = 0; it < 4; ++it) {
        float4 v = xp[tid + it * 256];
        s += (v.x + v.y) + (v.z + v.w);
    }
#pragma unroll
    for (int off = 32; off; off >>= 1) s += __shfl_down(s, off, 64);
    __shared__ float r[4];
    if ((tid & 63) == 0) r[tid >> 6] = s;
    __syncthreads();
    if (tid == 0) pooled[bid] = (r[0] + r[1] + r[2] + r[3]) * (1.f / 4096.f);
}

// ---- 2. attention: sigmoid(pooled @ att_w.T + att_b) -----------------------
__global__ void att_kernel(const float* __restrict__ pooled,
                           const float* __restrict__ aw,
                           const float* __restrict__ ab,
                           float* __restrict__ att, int b) {
    int n = blockIdx.x;                   // 32 blocks, 64 threads
    int t = threadIdx.x;
    float p = pooled[(b * 32 + n) * 64 + t];
#pragma unroll
    for (int k = 0; k < 4; ++k) {
        float v = p * aw[k * 64 + t];
#pragma unroll
        for (int off = 32; off; off >>= 1) v += __shfl_down(v, off, 64);
        if (t == 0) att[(b * 32 + n) * 4 + k] = 1.f / (1.f + expf(-(v + ab[k])));
    }
}

// ---- 3. expert-mix weights -> bf16, layout [n][tap][o][i] ------------------
template <int TAPS>
__global__ void __launch_bounds__(256) aggbf_kernel(const float* __restrict__ w,
                                                    const float* __restrict__ att,
                                                    unsigned* __restrict__ wbf, int b) {
    int idx = blockIdx.x * 256 + threadIdx.x;     // ((n*TAPS+t)*64+o)*32+ip
    if (idx >= 32 * TAPS * 2048) return;
    int ip = idx & 31;
    int o  = (idx >> 5) & 63;
    int t  = (idx >> 11) % TAPS;
    int n  = (idx >> 11) / TAPS;
    const float* a = att + (b * 32 + n) * 4;
    constexpr int PS = 64 * 64 * TAPS;
    int base = (o * 64 + ip * 2) * TAPS + t;      // w[k][o][i][t]
    float v0 = a[0]*w[base] + a[1]*w[PS+base] + a[2]*w[2*PS+base] + a[3]*w[3*PS+base];
    int base1 = base + TAPS;
    float v1 = a[0]*w[base1] + a[1]*w[PS+base1] + a[2]*w[2*PS+base1] + a[3]*w[3*PS+base1];
    wbf[idx] = bf16pair(v0, v1);
}

// ---- 4. MFMA conv: block = (4 rows, sample), 4 waves 2x2 of 32x32 ----------
#define LOADA(dst, tt) \
    _Pragma("unroll") for (int kk = 0; kk < 4; ++kk) dst[kk] = wp[(tt) * 512 + kk * 2];

#define TAPSTEP(tt, CUR) { \
    const int r_ = (tt) / KW, dw_ = (tt) % KW - PW; \
    const unsigned char* bp_ = xs + r_ * RSTR + hi * CSTR + (wcol + dw_ + 1) * 16; \
    _Pragma("unroll") for (int kk = 0; kk < 4; ++kk) { \
        const unsigned char* q_ = bp_ + kk * 2 * CSTR; \
        frag8 b0 = *(const frag8*)(q_); \
        frag8 b1 = *(const frag8*)(q_ + RSTR); \
        frag8 b2 = *(const frag8*)(q_ + 2 * RSTR); \
        frag8 b3 = *(const frag8*)(q_ + 3 * RSTR); \
        acc0 = __builtin_amdgcn_mfma_f32_32x32x16_bf16(CUR[kk], b0, acc0, 0, 0, 0); \
        acc1 = __builtin_amdgcn_mfma_f32_32x32x16_bf16(CUR[kk], b1, acc1, 0, 0, 0); \
        acc2 = __builtin_amdgcn_mfma_f32_32x32x16_bf16(CUR[kk], b2, acc2, 0, 0, 0); \
        acc3 = __builtin_amdgcn_mfma_f32_32x32x16_bf16(CUR[kk], b3, acc3, 0, 0, 0); \
    } }

template <int KH, int KW, int PH, int PW>
__global__ void __launch_bounds__(256) condconv_mfma(
    const float* __restrict__ x, const unsigned* __restrict__ wbf,
    float* __restrict__ out, float* __restrict__ pst, int cbase) {
    constexpr int TAPS = KH * KW;
    constexpr int HB = 4;
    constexpr int ROWS = HB + KH - 1;
    constexpr int CSTR = 1056;            // chunk stride bytes: 66 w-slots * 16
    constexpr int RSTR = 8 * CSTR;        // row stride bytes
    const int h0 = blockIdx.x * HB;
    const int n = blockIdx.y;
    const int tid = threadIdx.x;
    const int lane = tid & 63;
    const int wv = tid >> 6;
    const int wm = wv >> 1, wn = wv & 1;  // 2x2 wave grid (o-half, w-half)
    const int l31 = lane & 31, hi = lane >> 5;
    const int wcol = wn * 32 + l31;

    __shared__ __align__(16) unsigned char xs[ROWS * RSTR];
    __shared__ float red1[4][2][16], red2[4][2][16];

    // zero left/right halo w-slots (only used when KW>1)
    if (KW > 1 && tid < ROWS * 16) {
        int r = tid >> 4, c = (tid >> 1) & 7, e = tid & 1;
        *(uint4*)(xs + r * RSTR + c * CSTR + (e ? 65 : 0) * 16) = uint4{0, 0, 0, 0};
    }

    // stage ROWS input rows, chunk-major: 16 loads + 2 ds_write_b128 per thread/row
    {
        const int w = tid & 63, cg = tid >> 6;
        const float* xb = x + (size_t)(n * 256 + cbase) * HW;
        for (int r = 0; r < ROWS; ++r) {
            const int hin = h0 - PH + r;
            const bool rok = (KH == 1) || ((unsigned)hin < 64u);
#pragma unroll
            for (int half = 0; half < 2; ++half) {
                const int c = cg + half * 4;
                float v[8];
#pragma unroll
                for (int j = 0; j < 8; ++j)
                    v[j] = rok ? xb[(size_t)(c * 8 + j) * HW + hin * 64 + w] : 0.f;
                unsigned pk[4];
#pragma unroll
                for (int j = 0; j < 4; ++j) pk[j] = bf16pair(v[2 * j], v[2 * j + 1]);
                *(uint4*)(xs + r * RSTR + c * CSTR + (w + 1) * 16) = *(uint4*)pk;
            }
        }
    }

    // A-fragment base: frag f=kk*2+hi of row orow, tap t at wp[t*512 + kk*2]
    const frag8* wp = (const frag8*)wbf +
                      ((size_t)n * TAPS * 64 + wm * 32 + l31) * 8 + hi;

    frag8 aA[4], aB[4];
    LOADA(aA, 0);                          // overlaps staging
    __syncthreads();

    accf16 acc0 = {}, acc1 = {}, acc2 = {}, acc3 = {};
#pragma unroll
    for (int t = 0; t < TAPS; t += 2) {
        if (t + 1 < TAPS) LOADA(aB, t + 1);
        TAPSTEP(t, aA);
        if (t + 2 < TAPS) LOADA(aA, t + 2);
        if (t + 1 < TAPS) TAPSTEP(t + 1, aB);
    }

    // C write to shuffled channels (col=lane&31, row=(rg&3)+8*(rg>>2)+4*hi)
    {
        float* ob = out + (size_t)n * 256 * HW + h0 * 64 + wcol;
#pragma unroll
        for (int rg = 0; rg < 16; ++rg) {
            const int o = wm * 32 + (rg & 3) + 8 * (rg >> 2) + 4 * hi;
            float* p = ob + (size_t)shuf_ch(cbase + o) * HW;
            p[0]   = acc0[rg];
            p[64]  = acc1[rg];
            p[128] = acc2[rg];
            p[192] = acc3[rg];
        }
    }

    // BN partial sums -> unique slot per (o, n, h-block)
#pragma unroll
    for (int rg = 0; rg < 16; ++rg) {
        float v1 = acc0[rg] + acc1[rg] + acc2[rg] + acc3[rg];
        float v2 = acc0[rg] * acc0[rg] + acc1[rg] * acc1[rg] +
                   acc2[rg] * acc2[rg] + acc3[rg] * acc3[rg];
#pragma unroll
        for (int off = 16; off; off >>= 1) {
            v1 += __shfl_down(v1, off, 32);
            v2 += __shfl_down(v2, off, 32);
        }
        if (l31 == 0) { red1[wv][hi][rg] = v1; red2[wv][hi][rg] = v2; }
    }
    __syncthreads();
    if (tid < 64) {
        const int rg = tid & 15, hi2 = (tid >> 4) & 1, wm2 = tid >> 5;
        float s1 = red1[wm2 * 2][hi2][rg] + red1[wm2 * 2 + 1][hi2][rg];
        float s2 = red2[wm2 * 2][hi2][rg] + red2[wm2 * 2 + 1][hi2][rg];
        const int o = wm2 * 32 + (rg & 3) + 8 * (rg >> 2) + 4 * hi2;
        const int slot = n * 16 + blockIdx.x;           // 512 slots per channel
        pst[o * 1024 + slot] = s1;
        pst[o * 1024 + 512 + slot] = s2;
    }
}

// ---- 5. copy s0 (identity branch) into shuffled positions ------------------
__global__ void __launch_bounds__(256) s0_kernel(const float* __restrict__ x,
                                                 float* __restrict__ out) {
    int idx = blockIdx.x * 256 + threadIdx.x;
    int p4 = idx & 1023;
    int c = (idx >> 10) & 63;
    int n = idx >> 16;
    int c_out = shuf_ch(c);
    const float4* src = (const float4*)(x + (size_t)(n * 256 + c) * HW);
    float4* dst = (float4*)(out + (size_t)(n * 256 + c_out) * HW);
    dst[p4] = src[p4];
}

// ---- 6. reduce BN partials -> scale/shift ----------------------------------
__global__ void __launch_bounds__(256) bnstats_kernel(const float* __restrict__ pst,
                                                      const float* __restrict__ gamma,
                                                      const float* __restrict__ beta,
                                                      float* __restrict__ ss) {
    int o = blockIdx.x, t = threadIdx.x;
    float s1 = 0.f, s2 = 0.f;
    for (int i = t; i < 512; i += 256) {
        s1 += pst[o * 1024 + i];
        s2 += pst[o * 1024 + 512 + i];
    }
#pragma unroll
    for (int off = 32; off; off >>= 1) {
        s1 += __shfl_down(s1, off, 64);
        s2 += __shfl_down(s2, off, 64);
    }
    __shared__ float r1[4], r2[4];
    if ((t & 63) == 0) { r1[t >> 6] = s1; r2[t >> 6] = s2; }
    __syncthreads();
    if (t == 0) {
        float S1 = r1[0] + r1[1] + r1[2] + r1[3];
        float S2 = r2[0] + r2[1] + r2[2] + r2[3];
        float mean = S1 * CNT_INV;
        float var = S2 * CNT_INV - mean * mean;
        float scale = rsqrtf(var + 1e-5f) * gamma[o];
        ss[o * 2 + 0] = scale;
        ss[o * 2 + 1] = beta[o] - mean * scale;
    }
}

// ---- 7. apply BN in-place on d_out -----------------------------------------
__global__ void __launch_bounds__(256) bn_kernel(float* __restrict__ out,
                                                 const float* __restrict__ ss,
                                                 int cbase) {
    int bid = blockIdx.x;                 // 64*32*4 = 8192
    int chunk = bid & 3;
    int n = (bid >> 2) & 31;
    int o = bid >> 7;
    float scale = ss[o * 2], shift = ss[o * 2 + 1];
    int c_out = shuf_ch(cbase + o);
    float4* p = (float4*)(out + (size_t)(n * 256 + c_out) * HW) + chunk * 256 + threadIdx.x;
    float4 v = *p;
    v.x = fmaf(v.x, scale, shift);
    v.y = fmaf(v.y, scale, shift);
    v.z = fmaf(v.z, scale, shift);
    v.w = fmaf(v.w, scale, shift);
    *p = v;
}

extern "C" void kernel_launch(void* const* d_in, const int* in_sizes, int n_in,
                              void* d_out, int out_size, void* d_ws, size_t ws_size,
                              hipStream_t stream) {
    const float* x        = (const float*)d_in[0];
    const float* sq_att_w = (const float*)d_in[1];
    const float* sq_att_b = (const float*)d_in[2];
    const float* sq_w     = (const float*)d_in[3];
    const float* sq_g     = (const float*)d_in[4];
    const float* sq_b     = (const float*)d_in[5];
    const float* ver_att_w= (const float*)d_in[6];
    const float* ver_att_b= (const float*)d_in[7];
    const float* ver_w    = (const float*)d_in[8];
    const float* ver_g    = (const float*)d_in[9];
    const float* ver_b    = (const float*)d_in[10];
    const float* hor_att_w= (const float*)d_in[11];
    const float* hor_att_b= (const float*)d_in[12];
    const float* hor_w    = (const float*)d_in[13];
    const float* hor_g    = (const float*)d_in[14];
    const float* hor_b    = (const float*)d_in[15];
    float* out = (float*)d_out;
    float* ws = (float*)d_ws;

    float* pooled = ws + WS_POOLED;
    float* att    = ws + WS_ATT;
    float* ss     = ws + WS_SS;
    float* pst    = ws + WS_PST;
    unsigned* wbf_sq  = (unsigned*)(ws + WS_WBF_SQ);
    unsigned* wbf_ver = (unsigned*)(ws + WS_WBF_VER);
    unsigned* wbf_hor = (unsigned*)(ws + WS_WBF_HOR);

    pool_kernel<<<6144, 256, 0, stream>>>(x, pooled);
    att_kernel<<<32, 64, 0, stream>>>(pooled, sq_att_w, sq_att_b, att, 0);
    att_kernel<<<32, 64, 0, stream>>>(pooled, ver_att_w, ver_att_b, att, 1);
    att_kernel<<<32, 64, 0, stream>>>(pooled, hor_att_w, hor_att_b, att, 2);

    aggbf_kernel<9><<<2304, 256, 0, stream>>>(sq_w, att, wbf_sq, 0);
    aggbf_kernel<3><<<768, 256, 0, stream>>>(ver_w, att, wbf_ver, 1);
    aggbf_kernel<3><<<768, 256, 0, stream>>>(hor_w, att, wbf_hor, 2);

    condconv_mfma<3, 3, 1, 1><<<dim3(16, 32), 256, 0, stream>>>(x, wbf_sq, out, pst, 64);
    condconv_mfma<3, 1, 1, 0><<<dim3(16, 32), 256, 0, stream>>>(x, wbf_ver, out, pst + 65536, 128);
    condconv_mfma<1, 3, 0, 1><<<dim3(16, 32), 256, 0, stream>>>(x, wbf_hor, out, pst + 2 * 65536, 192);

    s0_kernel<<<8192, 256, 0, stream>>>(x, out);

    bnstats_kernel<<<64, 256, 0, stream>>>(pst, sq_g, sq_b, ss);
    bnstats_kernel<<<64, 256, 0, stream>>>(pst + 65536, ver_g, ver_b, ss + 128);
    bnstats_kernel<<<64, 256, 0, stream>>>(pst + 2 * 65536, hor_g, hor_b, ss + 256);

    bn_kernel<<<8192, 256, 0, stream>>>(out, ss, 64);
    bn_kernel<<<8192, 256, 0, stream>>>(out, ss + 128, 128);
    bn_kernel<<<8192, 256, 0, stream>>>(out, ss + 256, 192);
}

// Round 4
// 154.516 us; speedup vs baseline: 8.2739x; 1.1951x over previous
//
#include <hip/hip_runtime.h>
#include <cstddef>
#include <cstdint>

// ---------------------------------------------------------------------------
// x [N=32, C=256, H=64, W=64] fp32. Branches: sq 3x3 pad(1,1) ch 64..127,
// ver 3x1 pad(1,0) ch 128..191, hor 1x3 pad(0,1) ch 192..255. CondConv K=4.
// Training-mode BN per branch, concat(s0,sq,ve,ho), channel_shuffle(g=8):
//   c_out = (c_pre % 32)*8 + c_pre/32
// Conv: per-sample GEMM on matrix cores, bf16 in / fp32 accum.
// This round: 6 launches total (was 16). conv_all = sq+ver+hor+s0 in one
// grid (range dispatch). Conv wave layout (wn, row-half): each wave computes
// both o-halves x 2 rows -> 2 MFMA per ds_read_b128 (was 1).
// ---------------------------------------------------------------------------

typedef __attribute__((ext_vector_type(8))) short frag8;    // 8 bf16 = 4 VGPR
typedef __attribute__((ext_vector_type(16))) float accf16;  // 32x32 accum

#define HW 4096
#define CNT_INV (1.0f / 131072.0f)

// workspace offsets (4-byte units)
#define WS_POOLED 0            // 6144
#define WS_ATT    6144         // 384
#define WS_SS     6528         // 384 (3 * 128)
#define WS_PST    6912         // 3 * 65536
#define WS_WBF_SQ  203520      // 589824 u32 (bf16 pairs)
#define WS_WBF_VER 793344      // 196608
#define WS_WBF_HOR 989952      // 196608

__device__ __forceinline__ int shuf_ch(int c) { return ((c & 31) << 3) | (c >> 5); }

__device__ __forceinline__ unsigned bf16pair(float a, float b) {
    unsigned ua = __builtin_bit_cast(unsigned, a);
    unsigned ub = __builtin_bit_cast(unsigned, b);
    ua = (ua + 0x7fffu + ((ua >> 16) & 1u)) >> 16;   // round-to-nearest-even
    ub = (ub + 0x7fffu + ((ub >> 16) & 1u)) >> 16;
    return ua | (ub << 16);
}

// ---- 1. pooled mean over HxW for the 3 conv branches -----------------------
__global__ void __launch_bounds__(256) pool_kernel(const float* __restrict__ x,
                                                   float* __restrict__ pooled) {
    int bid = blockIdx.x;                 // (b*32+n)*64 + c, 6144 total
    int c = bid & 63;
    int n = (bid >> 6) & 31;
    int b = bid >> 11;
    const float4* xp = (const float4*)(x + (size_t)(n * 256 + 64 * (b + 1) + c) * HW);
    int tid = threadIdx.x;
    float s = 0.f;
#pragma unroll
    for (int it = 0; it < 4; ++it) {
        float4 v = xp[tid + it * 256];
        s += (v.x + v.y) + (v.z + v.w);
    }
#pragma unroll
    for (int off = 32; off; off >>= 1) s += __shfl_down(s, off, 64);
    __shared__ float r[4];
    if ((tid & 63) == 0) r[tid >> 6] = s;
    __syncthreads();
    if (tid == 0) pooled[bid] = (r[0] + r[1] + r[2] + r[3]) * (1.f / 4096.f);
}

// ---- 2. attention, all 3 branches: 96 blocks x 64 threads ------------------
__global__ void __launch_bounds__(64) att_all_kernel(
    const float* __restrict__ pooled,
    const float* __restrict__ aw0, const float* __restrict__ ab0,
    const float* __restrict__ aw1, const float* __restrict__ ab1,
    const float* __restrict__ aw2, const float* __restrict__ ab2,
    float* __restrict__ att) {
    int bid = blockIdx.x;                 // b*32+n
    int b = bid >> 5;
    const float* aw = (b == 0) ? aw0 : (b == 1) ? aw1 : aw2;
    const float* ab = (b == 0) ? ab0 : (b == 1) ? ab1 : ab2;
    int t = threadIdx.x;
    float p = pooled[bid * 64 + t];
#pragma unroll
    for (int k = 0; k < 4; ++k) {
        float v = p * aw[k * 64 + t];
#pragma unroll
        for (int off = 32; off; off >>= 1) v += __shfl_down(v, off, 64);
        if (t == 0) att[bid * 4 + k] = 1.f / (1.f + expf(-(v + ab[k])));
    }
}

// ---- 3. expert-mix weights -> bf16, layout [n][tap][o][i] ------------------
template <int TAPS>
__device__ __forceinline__ void aggbf_body(const float* __restrict__ w,
                                           const float* __restrict__ att,
                                           unsigned* __restrict__ wbf, int bid) {
    int idx = bid * 256 + threadIdx.x;            // ((n*TAPS+t)*64+o)*32+ip
    int ip = idx & 31;
    int o  = (idx >> 5) & 63;
    int t  = (idx >> 11) % TAPS;
    int n  = (idx >> 11) / TAPS;
    const float* a = att + n * 4;
    constexpr int PS = 64 * 64 * TAPS;
    int base = (o * 64 + ip * 2) * TAPS + t;      // w[k][o][i][t]
    float v0 = a[0]*w[base] + a[1]*w[PS+base] + a[2]*w[2*PS+base] + a[3]*w[3*PS+base];
    int base1 = base + TAPS;
    float v1 = a[0]*w[base1] + a[1]*w[PS+base1] + a[2]*w[2*PS+base1] + a[3]*w[3*PS+base1];
    wbf[idx] = bf16pair(v0, v1);
}

__global__ void __launch_bounds__(256) aggbf_all_kernel(
    const float* __restrict__ sq_w, const float* __restrict__ ver_w,
    const float* __restrict__ hor_w, const float* __restrict__ att,
    unsigned* __restrict__ wsq, unsigned* __restrict__ wver,
    unsigned* __restrict__ whor) {
    int bid = blockIdx.x;
    if (bid < 2304)      aggbf_body<9>(sq_w,  att,       wsq,  bid);
    else if (bid < 3072) aggbf_body<3>(ver_w, att + 128, wver, bid - 2304);
    else                 aggbf_body<3>(hor_w, att + 256, whor, bid - 3072);
}

// ---- 4. fused conv (3 branches) + s0 copy ----------------------------------
#define CSTR 1056
#define RSTR 8448

template <int KH, int KW, int PH, int PW>
__device__ __forceinline__ void conv_body(
    const float* __restrict__ x, const unsigned* __restrict__ wbf,
    float* __restrict__ out, float* __restrict__ pst, int cbase, int bid,
    unsigned char* xs, float (*red1)[2][2][16], float (*red2)[2][2][16]) {
    constexpr int TAPS = KH * KW;
    constexpr int HB = 4;
    constexpr int ROWS = HB + KH - 1;
    const int hb = bid & 15, n = bid >> 4;
    const int h0 = hb * HB;
    const int tid = threadIdx.x;
    const int lane = tid & 63;
    const int wv = tid >> 6;
    const int rh = wv >> 1, wn = wv & 1;  // wave = (row-half, w-half)
    const int l31 = lane & 31, hi = lane >> 5;
    const int wcol = wn * 32 + l31;

    // zero left/right halo w-slots (only used when KW>1)
    if (KW > 1 && tid < ROWS * 16) {
        int r = tid >> 4, c = (tid >> 1) & 7, e = tid & 1;
        *(uint4*)(xs + r * RSTR + c * CSTR + (e ? 65 : 0) * 16) = uint4{0, 0, 0, 0};
    }

    // stage ROWS input rows, chunk-major [row][ch/8][w+1] bf16
    {
        const int w = tid & 63, cg = tid >> 6;
        const float* xb = x + (size_t)(n * 256 + cbase) * HW;
        for (int r = 0; r < ROWS; ++r) {
            const int hin = h0 - PH + r;
            const bool rok = (KH == 1) || ((unsigned)hin < 64u);
#pragma unroll
            for (int half = 0; half < 2; ++half) {
                const int c = cg + half * 4;
                float v[8];
#pragma unroll
                for (int j = 0; j < 8; ++j)
                    v[j] = rok ? xb[(size_t)(c * 8 + j) * HW + hin * 64 + w] : 0.f;
                unsigned pk[4];
#pragma unroll
                for (int j = 0; j < 4; ++j) pk[j] = bf16pair(v[2 * j], v[2 * j + 1]);
                *(uint4*)(xs + r * RSTR + c * CSTR + (w + 1) * 16) = *(uint4*)pk;
            }
        }
    }

    // A fragments: frag f=kk*2+hi of row o, tap t at wp[t*512 + wm*256 + kk*2]
    const frag8* wp = (const frag8*)wbf + ((size_t)n * TAPS * 64 + l31) * 8 + hi;

    __syncthreads();

    accf16 a00 = {}, a01 = {}, a10 = {}, a11 = {};   // a{wm}{row}
#pragma unroll
    for (int t = 0; t < TAPS; ++t) {
        const int r_ = t / KW, dw = t % KW - PW;
        frag8 af[8];
#pragma unroll
        for (int kk = 0; kk < 4; ++kk) {
            af[kk]     = wp[t * 512 + kk * 2];
            af[4 + kk] = wp[t * 512 + 256 + kk * 2];
        }
        const unsigned char* bp = xs + (rh * 2 + r_) * RSTR + hi * CSTR +
                                  (wcol + dw + 1) * 16;
#pragma unroll
        for (int kk = 0; kk < 4; ++kk) {
            frag8 b0 = *(const frag8*)(bp + kk * 2 * CSTR);
            frag8 b1 = *(const frag8*)(bp + kk * 2 * CSTR + RSTR);
            a00 = __builtin_amdgcn_mfma_f32_32x32x16_bf16(af[kk],     b0, a00, 0, 0, 0);
            a10 = __builtin_amdgcn_mfma_f32_32x32x16_bf16(af[4 + kk], b0, a10, 0, 0, 0);
            a01 = __builtin_amdgcn_mfma_f32_32x32x16_bf16(af[kk],     b1, a01, 0, 0, 0);
            a11 = __builtin_amdgcn_mfma_f32_32x32x16_bf16(af[4 + kk], b1, a11, 0, 0, 0);
        }
    }

    // C write: rows h0+rh*2, h0+rh*2+1; both o-halves
    {
        float* ob = out + (size_t)n * 256 * HW + (h0 + rh * 2) * 64 + wcol;
#pragma unroll
        for (int rg = 0; rg < 16; ++rg) {
            const int o = (rg & 3) + 8 * (rg >> 2) + 4 * hi;
            float* p0 = ob + (size_t)shuf_ch(cbase + o) * HW;
            p0[0]  = a00[rg];
            p0[64] = a01[rg];
            float* p1 = ob + (size_t)shuf_ch(cbase + 32 + o) * HW;
            p1[0]  = a10[rg];
            p1[64] = a11[rg];
        }
    }

    // BN partial sums
#pragma unroll
    for (int rg = 0; rg < 16; ++rg) {
        float u1 = a00[rg] + a01[rg];
        float u2 = a00[rg] * a00[rg] + a01[rg] * a01[rg];
        float w1 = a10[rg] + a11[rg];
        float w2 = a10[rg] * a10[rg] + a11[rg] * a11[rg];
#pragma unroll
        for (int off = 16; off; off >>= 1) {
            u1 += __shfl_down(u1, off, 32);
            u2 += __shfl_down(u2, off, 32);
            w1 += __shfl_down(w1, off, 32);
            w2 += __shfl_down(w2, off, 32);
        }
        if (l31 == 0) {
            red1[wv][0][hi][rg] = u1; red2[wv][0][hi][rg] = u2;
            red1[wv][1][hi][rg] = w1; red2[wv][1][hi][rg] = w2;
        }
    }
    __syncthreads();
    if (tid < 64) {
        const int rg = tid & 15, hi2 = (tid >> 4) & 1, wm2 = tid >> 5;
        float s1 = 0.f, s2 = 0.f;
#pragma unroll
        for (int v = 0; v < 4; ++v) {
            s1 += red1[v][wm2][hi2][rg];
            s2 += red2[v][wm2][hi2][rg];
        }
        const int o = wm2 * 32 + (rg & 3) + 8 * (rg >> 2) + 4 * hi2;
        const int slot = n * 16 + hb;
        pst[o * 1024 + slot] = s1;
        pst[o * 1024 + 512 + slot] = s2;
    }
}

__device__ __forceinline__ void s0_body(const float* __restrict__ x,
                                        float* __restrict__ out, int bid) {
    const int n = bid >> 4, c0 = (bid & 15) * 4, tid = threadIdx.x;
#pragma unroll
    for (int j = 0; j < 4; ++j) {
        const int c = c0 + j;
        const float4* s = (const float4*)(x + (size_t)(n * 256 + c) * HW);
        float4* d = (float4*)(out + (size_t)(n * 256 + shuf_ch(c)) * HW);
#pragma unroll
        for (int it = 0; it < 4; ++it) d[tid + it * 256] = s[tid + it * 256];
    }
}

__global__ void __launch_bounds__(256, 3) conv_all_kernel(
    const float* __restrict__ x, const unsigned* __restrict__ wsq,
    const unsigned* __restrict__ wver, const unsigned* __restrict__ whor,
    float* __restrict__ out, float* __restrict__ pst) {
    __shared__ __align__(16) unsigned char xs[6 * RSTR];
    __shared__ float red1[4][2][2][16], red2[4][2][2][16];
    int bid = blockIdx.x;
    if (bid < 512)
        conv_body<3, 3, 1, 1>(x, wsq, out, pst, 64, bid, xs, red1, red2);
    else if (bid < 1024)
        conv_body<3, 1, 1, 0>(x, wver, out, pst + 65536, 128, bid - 512, xs, red1, red2);
    else if (bid < 1536)
        conv_body<1, 3, 0, 1>(x, whor, out, pst + 131072, 192, bid - 1024, xs, red1, red2);
    else
        s0_body(x, out, bid - 1536);
}

// ---- 5. reduce BN partials -> scale/shift, all branches --------------------
__global__ void __launch_bounds__(256) bnstats_all_kernel(
    const float* __restrict__ pst,
    const float* __restrict__ g0, const float* __restrict__ b0,
    const float* __restrict__ g1, const float* __restrict__ b1,
    const float* __restrict__ g2, const float* __restrict__ b2,
    float* __restrict__ ss) {
    int br = blockIdx.x >> 6, o = blockIdx.x & 63, t = threadIdx.x;
    const float* gamma = (br == 0) ? g0 : (br == 1) ? g1 : g2;
    const float* beta  = (br == 0) ? b0 : (br == 1) ? b1 : b2;
    const float* p = pst + br * 65536 + o * 1024;
    float s1 = 0.f, s2 = 0.f;
    for (int i = t; i < 512; i += 256) {
        s1 += p[i];
        s2 += p[512 + i];
    }
#pragma unroll
    for (int off = 32; off; off >>= 1) {
        s1 += __shfl_down(s1, off, 64);
        s2 += __shfl_down(s2, off, 64);
    }
    __shared__ float r1[4], r2[4];
    if ((t & 63) == 0) { r1[t >> 6] = s1; r2[t >> 6] = s2; }
    __syncthreads();
    if (t == 0) {
        float S1 = r1[0] + r1[1] + r1[2] + r1[3];
        float S2 = r2[0] + r2[1] + r2[2] + r2[3];
        float mean = S1 * CNT_INV;
        float var = S2 * CNT_INV - mean * mean;
        float scale = rsqrtf(var + 1e-5f) * gamma[o];
        ss[br * 128 + o * 2 + 0] = scale;
        ss[br * 128 + o * 2 + 1] = beta[o] - mean * scale;
    }
}

// ---- 6. apply BN in-place on d_out, all branches ---------------------------
__global__ void __launch_bounds__(256) bn_all_kernel(float* __restrict__ out,
                                                     const float* __restrict__ ss) {
    int gbid = blockIdx.x;                // 3 * 8192
    int sub = gbid >> 13;
    int bid = gbid & 8191;
    int chunk = bid & 3;
    int n = (bid >> 2) & 31;
    int o = bid >> 7;
    float scale = ss[sub * 128 + o * 2], shift = ss[sub * 128 + o * 2 + 1];
    int c_out = shuf_ch(64 * (sub + 1) + o);
    float4* p = (float4*)(out + (size_t)(n * 256 + c_out) * HW) + chunk * 256 + threadIdx.x;
    float4 v = *p;
    v.x = fmaf(v.x, scale, shift);
    v.y = fmaf(v.y, scale, shift);
    v.z = fmaf(v.z, scale, shift);
    v.w = fmaf(v.w, scale, shift);
    *p = v;
}

extern "C" void kernel_launch(void* const* d_in, const int* in_sizes, int n_in,
                              void* d_out, int out_size, void* d_ws, size_t ws_size,
                              hipStream_t stream) {
    const float* x        = (const float*)d_in[0];
    const float* sq_att_w = (const float*)d_in[1];
    const float* sq_att_b = (const float*)d_in[2];
    const float* sq_w     = (const float*)d_in[3];
    const float* sq_g     = (const float*)d_in[4];
    const float* sq_b     = (const float*)d_in[5];
    const float* ver_att_w= (const float*)d_in[6];
    const float* ver_att_b= (const float*)d_in[7];
    const float* ver_w    = (const float*)d_in[8];
    const float* ver_g    = (const float*)d_in[9];
    const float* ver_b    = (const float*)d_in[10];
    const float* hor_att_w= (const float*)d_in[11];
    const float* hor_att_b= (const float*)d_in[12];
    const float* hor_w    = (const float*)d_in[13];
    const float* hor_g    = (const float*)d_in[14];
    const float* hor_b    = (const float*)d_in[15];
    float* out = (float*)d_out;
    float* ws = (float*)d_ws;

    float* pooled = ws + WS_POOLED;
    float* att    = ws + WS_ATT;
    float* ss     = ws + WS_SS;
    float* pst    = ws + WS_PST;
    unsigned* wbf_sq  = (unsigned*)(ws + WS_WBF_SQ);
    unsigned* wbf_ver = (unsigned*)(ws + WS_WBF_VER);
    unsigned* wbf_hor = (unsigned*)(ws + WS_WBF_HOR);

    pool_kernel<<<6144, 256, 0, stream>>>(x, pooled);
    att_all_kernel<<<96, 64, 0, stream>>>(pooled, sq_att_w, sq_att_b,
                                          ver_att_w, ver_att_b,
                                          hor_att_w, hor_att_b, att);
    aggbf_all_kernel<<<3840, 256, 0, stream>>>(sq_w, ver_w, hor_w, att,
                                               wbf_sq, wbf_ver, wbf_hor);
    conv_all_kernel<<<2048, 256, 0, stream>>>(x, wbf_sq, wbf_ver, wbf_hor, out, pst);
    bnstats_all_kernel<<<192, 256, 0, stream>>>(pst, sq_g, sq_b, ver_g, ver_b,
                                                hor_g, hor_b, ss);
    bn_all_kernel<<<24576, 256, 0, stream>>>(out, ss);
}